// Round 8
// baseline (302.943 us; speedup 1.0000x reference)
//
#include <hip/hip_runtime.h>
#include <hip/hip_bf16.h>
#include <math.h>

#define D 128
#define BSHIFT 6                 // 64 dst nodes per bucket
#define BSIZE 64
#define MAXB 2048                // max buckets (phase1 LDS arrays)
#define MAXWG 512                // max partition WGs (mega LDS arrays)
#define PCHUNK 4096              // edges per partition WG
#define PE 16                    // PCHUNK / 256
#define EB_CAP 1408              // LDS edge cap per bucket (mean 1024, +12 sigma)
#define PR 2048                  // fallback per-bucket global region
#define FB_CHUNK 512

// ---------- helpers ----------
__device__ __forceinline__ unsigned short f2bf(float f) {
    union { float f; unsigned int u; } c; c.f = f;
    unsigned int u = c.u;
    unsigned int r = (u + 0x7FFFu + ((u >> 16) & 1u)) >> 16;  // RNE
    return (unsigned short)r;
}
__device__ __forceinline__ void unpack2(unsigned int w, float& lo, float& hi) {
    union { unsigned int u; float f; } c;
    c.u = w << 16;          lo = c.f;
    c.u = w & 0xFFFF0000u;  hi = c.f;
}

// ---------- phase1: fused [partition blocks | prep blocks] ----------
__global__ __launch_bounds__(256) void phase1_kernel(
        const float* __restrict__ feat_src, const float* __restrict__ feat_dst,
        const float* __restrict__ attn_l,  const float* __restrict__ attn_r,
        float* __restrict__ el, float* __restrict__ er,
        unsigned short* __restrict__ feat_bf,
        const int* __restrict__ src, const int* __restrict__ dst,
        int E, int nbk, int nwg,
        unsigned* __restrict__ bins, int* __restrict__ cnt_tab, int* __restrict__ loc_tab,
        int Ns, int Nd) {
    __shared__ int hist[MAXB];
    __shared__ int lstart[MAXB];
    __shared__ int cursor[MAXB];
    __shared__ unsigned sbuf[PCHUNK];      // 16 KB
    int tid = threadIdx.x;

    if ((int)blockIdx.x < nwg) {
        int w = blockIdx.x;
        int e0 = w * PCHUNK;
        int e1 = min(E, e0 + PCHUNK);
        int n = e1 - e0;

        for (int i = tid; i < nbk; i += 256) hist[i] = 0;
        __syncthreads();

        unsigned pv[PE]; int bk[PE];
        #pragma unroll
        for (int k = 0; k < PE; ++k) {
            int idx = e0 + k * 256 + tid;
            if (idx < e1) {
                int s = src[idx], j = dst[idx];
                bk[k] = j >> BSHIFT;
                pv[k] = (unsigned)s | ((unsigned)(j & (BSIZE - 1)) << 24);
                atomicAdd(&hist[bk[k]], 1);
            }
        }
        __syncthreads();

        if (tid < 64) {                    // wave-0 exclusive scan of hist
            int carry = 0;
            for (int c = 0; c < nbk; c += 64) {
                int i = c + tid;
                int v = (i < nbk) ? hist[i] : 0;
                int x = v;
                #pragma unroll
                for (int off = 1; off < 64; off <<= 1) {
                    int t = __shfl_up(x, off, 64);
                    if (tid >= off) x += t;
                }
                if (i < nbk) lstart[i] = x - v + carry;
                carry += __shfl(x, 63, 64);
            }
        }
        __syncthreads();

        for (int i = tid; i < nbk; i += 256) {
            cnt_tab[(size_t)w * nbk + i] = hist[i];
            loc_tab[(size_t)w * nbk + i] = lstart[i];
            cursor[i] = 0;
        }
        __syncthreads();

        #pragma unroll
        for (int k = 0; k < PE; ++k) {
            int idx = e0 + k * 256 + tid;
            if (idx < e1) {
                int b = bk[k];
                int r = lstart[b] + atomicAdd(&cursor[b], 1);
                sbuf[r] = pv[k];
            }
        }
        __syncthreads();

        unsigned* obase = bins + (size_t)w * PCHUNK;
        for (int t = tid; t < n; t += 256) obase[t] = sbuf[t];   // coalesced
    } else {
        // prep block: 8 nodes, float4 per 32-lane half-wave
        int blk = blockIdx.x - nwg;
        int half = tid >> 5, lane = tid & 31;
        int node = blk * 8 + half;
        if (node >= Ns + Nd) return;
        bool is_src = node < Ns;
        const float* feat = is_src ? feat_src + (size_t)node * D
                                   : feat_dst + (size_t)(node - Ns) * D;
        const float* attn = is_src ? attn_l : attn_r;
        float4 a = ((const float4*)attn)[lane];
        float4 v = ((const float4*)feat)[lane];
        if (is_src) {
            ushort4 h; h.x = f2bf(v.x); h.y = f2bf(v.y); h.z = f2bf(v.z); h.w = f2bf(v.w);
            ((ushort4*)(feat_bf + (size_t)node * D))[lane] = h;
        }
        float s = v.x * a.x + v.y * a.y + v.z * a.z + v.w * a.w;
        #pragma unroll
        for (int off = 16; off > 0; off >>= 1)
            s += __shfl_xor(s, off, 64);
        if (lane == 0) {
            if (is_src) el[node] = s;
            else        er[node - Ns] = s;
        }
    }
}

// ---------- mega: stage -> count -> scan -> rank -> weights -> softmax -> aggregate ----------
// One 256-thread block per 64-dst bucket; no global scratch in the fast path.
__global__ __launch_bounds__(256) void mega_kernel(
        const unsigned* __restrict__ bins,
        const int* __restrict__ cnt_tab, const int* __restrict__ loc_tab,
        int nbk, int nwg,
        const unsigned short* __restrict__ feat_bf,
        const float* __restrict__ el, const float* __restrict__ er,
        int* __restrict__ fb_perm, float* __restrict__ fb_w,
        float* __restrict__ out, int Nd) {
    __shared__ unsigned raw[EB_CAP];       // staged packed edges; reused as W (float)
    __shared__ unsigned ord[EB_CAP];       // ranked (grouped by dst)
    __shared__ int wcnt[MAXWG], wdst[MAXWG], wloc[MAXWG];
    __shared__ int cnt64[BSIZE], off64[BSIZE], cur64[BSIZE];
    __shared__ float invf[BSIZE];
    __shared__ int total_sh;

    int b = blockIdx.x, tid = threadIdx.x;
    int base = b << BSHIFT;

    for (int i = tid; i < nwg; i += 256) {
        wcnt[i] = cnt_tab[(size_t)i * nbk + b];
        wloc[i] = loc_tab[(size_t)i * nbk + b];
    }
    if (tid < BSIZE) { cnt64[tid] = 0; cur64[tid] = 0; }
    __syncthreads();
    if (tid < 64) {                        // exclusive scan over segment counts
        int carry = 0;
        for (int c = 0; c < nwg; c += 64) {
            int i = c + tid;
            int v = (i < nwg) ? wcnt[i] : 0;
            int x = v;
            #pragma unroll
            for (int off = 1; off < 64; off <<= 1) {
                int t = __shfl_up(x, off, 64);
                if (tid >= off) x += t;
            }
            if (i < nwg) wdst[i] = x - v + carry;
            carry += __shfl(x, 63, 64);
        }
        if (tid == 0) total_sh = carry;
    }
    __syncthreads();
    int n = total_sh;
    bool fits = (n <= EB_CAP);

    if (fits) {
        // stage: thread t -> element t; segment located by binary search (upper bound)
        for (int t = tid; t < n; t += 256) {
            int lo = 0, hi = nwg - 1;
            while (lo < hi) { int mid = (lo + hi + 1) >> 1; if (wdst[mid] <= t) lo = mid; else hi = mid - 1; }
            raw[t] = bins[(size_t)lo * PCHUNK + wloc[lo] + (t - wdst[lo])];
        }
        __syncthreads();
        for (int t = tid; t < n; t += 256)
            atomicAdd(&cnt64[raw[t] >> 24], 1);
    } else {
        // statistically unreachable: count straight from global
        for (int w = tid; w < nwg; w += 256) {
            int c = wcnt[w];
            const unsigned* sp = bins + (size_t)w * PCHUNK + wloc[w];
            for (int k = 0; k < c; ++k)
                atomicAdd(&cnt64[sp[k] >> 24], 1);
        }
    }
    __syncthreads();

    // 64-wide exclusive scan of per-dst counts (wave 0, single chunk)
    if (tid < 64) {
        int v = cnt64[tid];
        int x = v;
        #pragma unroll
        for (int off = 1; off < 64; off <<= 1) {
            int t = __shfl_up(x, off, 64);
            if (tid >= off) x += t;
        }
        int o = x - v;
        if (!fits) {                       // paranoia clamp for global region
            if (o > PR) o = PR;
            if (o + v > PR) v = PR - o;
            cnt64[tid] = v;
        }
        off64[tid] = o;
    }
    __syncthreads();

    // rank (grouped-by-dst order)
    if (fits) {
        for (int t = tid; t < n; t += 256) {
            unsigned e = raw[t];
            int d = e >> 24;
            int r = atomicAdd(&cur64[d], 1);
            ord[off64[d] + r] = e;
        }
    } else {
        unsigned* op = (unsigned*)fb_perm + (size_t)b * PR;
        for (int w = tid; w < nwg; w += 256) {
            int c0 = wcnt[w];
            const unsigned* sp = bins + (size_t)w * PCHUNK + wloc[w];
            for (int k = 0; k < c0; ++k) {
                unsigned e = sp[k];
                int d = e >> 24;
                int r = atomicAdd(&cur64[d], 1);
                if (r < cnt64[d]) op[off64[d] + r] = e;
            }
        }
    }
    __syncthreads();

    int neff = fits ? n : min(n, PR);
    const unsigned* ORD = fits ? (const unsigned*)ord
                               : (const unsigned*)fb_perm + (size_t)b * PR;
    float* W = fits ? (float*)raw : (fb_w + (size_t)b * PR);

    // per-edge leaky(e)
    for (int t = tid; t < neff; t += 256) {
        unsigned e = ORD[t];
        int s = (int)(e & 0xFFFFFFu);
        int d = (int)(e >> 24);
        float x = el[s] + er[base + d];
        x = (x >= 0.0f) ? x : 0.01f * x;
        W[t] = x;
    }
    __syncthreads();

    // per-dst softmax (thread d handles dst d); inv denom -> invf
    if (tid < BSIZE) {
        int c = cnt64[tid], o = off64[tid];
        float iv = 0.0f;
        if (c > 0) {
            float m = -INFINITY;
            for (int k = 0; k < c; ++k) m = fmaxf(m, W[o + k]);
            float s2 = 0.0f;
            for (int k = 0; k < c; ++k) { float a = __expf(W[o + k] - m); W[o + k] = a; s2 += a; }
            iv = 1.0f / s2;
        }
        invf[tid] = iv;
    }
    __syncthreads();

    // aggregate: wave wv handles dsts wv, wv+4, ...; lane owns 2 features (4B row load)
    int wv = tid >> 6, lane = tid & 63;
    for (int d = wv; d < BSIZE; d += 4) {
        int gd = base + d;
        if (gd >= Nd) break;
        int c = cnt64[d], o = off64[d];
        float a0 = 0.0f, a1 = 0.0f;
        for (int k = 0; k < c; ++k) {
            unsigned e = ORD[o + k];       // broadcast
            float wt = W[o + k];           // broadcast
            unsigned pvv = *(const unsigned*)(feat_bf + (size_t)(e & 0xFFFFFFu) * D + lane * 2);
            float flo, fhi; unpack2(pvv, flo, fhi);
            a0 += wt * flo; a1 += wt * fhi;
        }
        float iv = invf[d];
        float2 r2; r2.x = a0 * iv; r2.y = a1 * iv;
        ((float2*)(out + (size_t)gd * D))[lane] = r2;
    }
}

// ================= fallback pipeline (shape/workspace out of range) =================
__global__ void prep_fb_kernel(const float* __restrict__ feat_src,
                               const float* __restrict__ feat_dst,
                               const float* __restrict__ attn_l,
                               const float* __restrict__ attn_r,
                               float* __restrict__ el, float* __restrict__ er,
                               int Ns, int Nd) {
    int half = threadIdx.x >> 5, lane = threadIdx.x & 31;
    int node = blockIdx.x * 8 + half;
    if (node >= Ns + Nd) return;
    bool is_src = node < Ns;
    const float* feat = is_src ? feat_src + (size_t)node * D
                               : feat_dst + (size_t)(node - Ns) * D;
    const float* attn = is_src ? attn_l : attn_r;
    float4 a = ((const float4*)attn)[lane];
    float4 v = ((const float4*)feat)[lane];
    float s = v.x * a.x + v.y * a.y + v.z * a.z + v.w * a.w;
    #pragma unroll
    for (int off = 16; off > 0; off >>= 1)
        s += __shfl_xor(s, off, 64);
    if (lane == 0) {
        if (is_src) el[node] = s;
        else        er[node - Ns] = s;
    }
}
__global__ void hist_kernel(const int* __restrict__ dst, int E, int* __restrict__ counts) {
    int stride = gridDim.x * blockDim.x;
    for (int k = blockIdx.x * blockDim.x + threadIdx.x; k < E; k += stride)
        atomicAdd(&counts[dst[k]], 1);
}
__global__ void scan1_kernel(const int* __restrict__ counts, int* __restrict__ offsets,
                             int* __restrict__ blockSums, int N) {
    __shared__ int tile[256];
    int tid = threadIdx.x;
    int i = blockIdx.x * 256 + tid;
    int v = (i < N) ? counts[i] : 0;
    tile[tid] = v;
    __syncthreads();
    for (int off = 1; off < 256; off <<= 1) {
        int t = (tid >= off) ? tile[tid - off] : 0;
        __syncthreads();
        tile[tid] += t;
        __syncthreads();
    }
    int incl = tile[tid];
    if (i < N) offsets[i] = incl - v;
    if (tid == 255) blockSums[blockIdx.x] = incl;
}
__global__ void scan2_kernel(int* __restrict__ bs, int nb) {
    __shared__ int tile[256];
    int tid = threadIdx.x;
    int carry = 0;
    for (int base = 0; base < nb; base += 256) {
        int i = base + tid;
        int v = (i < nb) ? bs[i] : 0;
        __syncthreads();
        tile[tid] = v;
        __syncthreads();
        for (int off = 1; off < 256; off <<= 1) {
            int t = (tid >= off) ? tile[tid - off] : 0;
            __syncthreads();
            tile[tid] += t;
            __syncthreads();
        }
        int incl = tile[tid];
        if (i < nb) bs[i] = incl - v + carry;
        carry += tile[255];
    }
}
__global__ void fill_kernel(const int* __restrict__ src, const int* __restrict__ dst, int E,
                            const int* __restrict__ offsets, const int* __restrict__ bsum,
                            int* __restrict__ cursor, int* __restrict__ perm_src) {
    int stride = gridDim.x * blockDim.x;
    for (int k = blockIdx.x * blockDim.x + threadIdx.x; k < E; k += stride) {
        int j = dst[k];
        int p = offsets[j] + bsum[j >> 8] + atomicAdd(&cursor[j], 1);
        perm_src[p] = src[k];
    }
}
__device__ __forceinline__ float block_max128(float v, float* red, int tid) {
    #pragma unroll
    for (int off = 32; off > 0; off >>= 1)
        v = fmaxf(v, __shfl_down(v, off, 64));
    __syncthreads();
    if ((tid & 63) == 0) red[tid >> 6] = v;
    __syncthreads();
    return fmaxf(red[0], red[1]);
}
__device__ __forceinline__ float block_sum128(float v, float* red, int tid) {
    #pragma unroll
    for (int off = 32; off > 0; off >>= 1)
        v += __shfl_down(v, off, 64);
    __syncthreads();
    if ((tid & 63) == 0) red[tid >> 6] = v;
    __syncthreads();
    return red[0] + red[1];
}
__global__ void gat_aggregate_f32_kernel(const float* __restrict__ feat_src,
                                         const float* __restrict__ el,
                                         const float* __restrict__ er,
                                         const int* __restrict__ offsets,
                                         const int* __restrict__ bsum,
                                         const int* __restrict__ counts,
                                         const int* __restrict__ perm_src,
                                         float* __restrict__ out, int Nd) {
    __shared__ float w_sh[FB_CHUNK];
    __shared__ int   s_sh[FB_CHUNK];
    __shared__ float red[2];
    int j = blockIdx.x;
    int tid = threadIdx.x;
    int cnt = counts[j];
    size_t orow = (size_t)j * D;
    if (cnt == 0) { out[orow + tid] = 0.0f; return; }
    int beg = offsets[j] + bsum[j >> 8];
    float erj = er[j];
    float acc = 0.0f;
    float inv;
    if (cnt <= FB_CHUNK) {
        float lmax = -INFINITY;
        for (int t = tid; t < cnt; t += 128) {
            int s = perm_src[beg + t];
            float e = el[s] + erj;
            e = (e >= 0.0f) ? e : 0.01f * e;
            s_sh[t] = s; w_sh[t] = e;
            lmax = fmaxf(lmax, e);
        }
        float m = block_max128(lmax, red, tid);
        float lsum = 0.0f;
        for (int t = tid; t < cnt; t += 128) {
            float a = __expf(w_sh[t] - m);
            w_sh[t] = a; lsum += a;
        }
        float den = block_sum128(lsum, red, tid);
        inv = 1.0f / den;
        __syncthreads();
        for (int t = 0; t < cnt; ++t)
            acc += feat_src[(size_t)s_sh[t] * D + tid] * w_sh[t];
    } else {
        float lmax = -INFINITY;
        for (int t = tid; t < cnt; t += 128) {
            int s = perm_src[beg + t];
            float e = el[s] + erj;
            e = (e >= 0.0f) ? e : 0.01f * e;
            lmax = fmaxf(lmax, e);
        }
        float m = block_max128(lmax, red, tid);
        float lsum = 0.0f;
        for (int t = tid; t < cnt; t += 128) {
            int s = perm_src[beg + t];
            float e = el[s] + erj;
            e = (e >= 0.0f) ? e : 0.01f * e;
            lsum += __expf(e - m);
        }
        float den = block_sum128(lsum, red, tid);
        inv = 1.0f / den;
        for (int bb = 0; bb < cnt; bb += FB_CHUNK) {
            int n = min(FB_CHUNK, cnt - bb);
            __syncthreads();
            for (int t = tid; t < n; t += 128) {
                int s = perm_src[beg + bb + t];
                float e = el[s] + erj;
                e = (e >= 0.0f) ? e : 0.01f * e;
                s_sh[t] = s;
                w_sh[t] = __expf(e - m);
            }
            __syncthreads();
            for (int t = 0; t < n; ++t)
                acc += feat_src[(size_t)s_sh[t] * D + tid] * w_sh[t];
        }
    }
    out[orow + tid] = acc * inv;
}

extern "C" void kernel_launch(void* const* d_in, const int* in_sizes, int n_in,
                              void* d_out, int out_size, void* d_ws, size_t ws_size,
                              hipStream_t stream) {
    const float* feat_src = (const float*)d_in[0];
    const float* feat_dst = (const float*)d_in[1];
    const int*   src      = (const int*)d_in[2];
    const int*   dst      = (const int*)d_in[3];
    const float* attn_l   = (const float*)d_in[4];
    const float* attn_r   = (const float*)d_in[5];
    float* out = (float*)d_out;

    int Ns = in_sizes[0] / D;
    int Nd = in_sizes[1] / D;
    int E  = in_sizes[2];
    int NBK = (Nd + BSIZE - 1) >> BSHIFT;
    int NWG = (E + PCHUNK - 1) / PCHUNK;
    int NBK8 = (Nd + 255) / 256;           // fallback scan blocks

    char* p = (char*)d_ws;
    auto carve = [&](size_t bytes) { void* r = (void*)p; p += (bytes + 255) & ~(size_t)255; return r; };
    float*    el      = (float*)carve((size_t)Ns * 4);
    float*    er      = (float*)carve((size_t)Nd * 4);
    int*      counts  = (int*)carve((size_t)Nd * 4);      // fallback only
    int*      offs    = (int*)carve((size_t)Nd * 4);      // fallback only
    int*      gcursor = (int*)carve((size_t)Nd * 4);      // fallback only
    int*      bsums   = (int*)carve((size_t)NBK8 * 4);    // fallback only
    int*      cnt_tab = (int*)carve((size_t)NWG * NBK * 4);
    int*      loc_tab = (int*)carve((size_t)NWG * NBK * 4);
    int*      fb_perm = (int*)carve((size_t)NBK * PR * 4);   // >= E*4; fallback perm too
    float*    fb_w    = (float*)carve((size_t)NBK * PR * 4);
    unsigned* bins    = (unsigned*)carve((size_t)NWG * PCHUNK * 4);
    size_t used       = (size_t)(p - (char*)d_ws);
    size_t bf_bytes   = (size_t)Ns * D * 2;
    unsigned short* feat_bf = (unsigned short*)carve(bf_bytes);

    int fast = (NBK <= MAXB && NWG <= MAXWG && Ns <= (1 << 24) &&
                used + bf_bytes + 256 <= ws_size) ? 1 : 0;

    int total = Ns + Nd;
    int prep_blocks = (total + 7) / 8;
    if (fast) {
        phase1_kernel<<<NWG + prep_blocks, 256, 0, stream>>>(
            feat_src, feat_dst, attn_l, attn_r, el, er, feat_bf,
            src, dst, E, NBK, NWG, bins, cnt_tab, loc_tab, Ns, Nd);
        mega_kernel<<<NBK, 256, 0, stream>>>(bins, cnt_tab, loc_tab, NBK, NWG,
                                             feat_bf, el, er, fb_perm, fb_w, out, Nd);
    } else {
        hipMemsetAsync(counts, 0, (size_t)Nd * 4, stream);
        hipMemsetAsync(gcursor, 0, (size_t)Nd * 4, stream);
        prep_fb_kernel<<<prep_blocks, 256, 0, stream>>>(feat_src, feat_dst, attn_l, attn_r,
                                                        el, er, Ns, Nd);
        hist_kernel<<<2048, 256, 0, stream>>>(dst, E, counts);
        scan1_kernel<<<NBK8, 256, 0, stream>>>(counts, offs, bsums, Nd);
        scan2_kernel<<<1, 256, 0, stream>>>(bsums, NBK8);
        fill_kernel<<<2048, 256, 0, stream>>>(src, dst, E, offs, bsums, gcursor, fb_perm);
        gat_aggregate_f32_kernel<<<Nd, 128, 0, stream>>>(feat_src, el, er, offs,
                                                         bsums, counts, fb_perm, out, Nd);
    }
}